// Round 2
// baseline (331.985 us; speedup 1.0000x reference)
//
#include <hip/hip_runtime.h>
#include <stdint.h>

#define IDIM 2048
#define HDIM 2048
#define CDIM 4096
#define BDIM 4096
#define KDIM 4096

typedef float f32x4 __attribute__((ext_vector_type(4)));
typedef short s16x8 __attribute__((ext_vector_type(8)));
typedef unsigned short u16;
typedef u16 u16x8 __attribute__((ext_vector_type(8)));

__device__ __forceinline__ u16 f2bf(float f) {
    union { float f; uint32_t u; } v; v.f = f;
    uint32_t r = v.u + 0x7fffu + ((v.u >> 16) & 1u);  // round-to-nearest-even
    return (u16)(r >> 16);
}

__device__ __forceinline__ void gload_lds16(const void* g, void* l) {
    __builtin_amdgcn_global_load_lds(
        (__attribute__((address_space(1))) void*)g,
        (__attribute__((address_space(3))) void*)l,
        16, 0, 0);
}

// flat f32 -> bf16 convert, 8 elements per thread
__global__ void cvt_bf16_kernel(const float* __restrict__ src, u16* __restrict__ dst,
                                int ngroups) {
    int i = blockIdx.x * blockDim.x + threadIdx.x;
    if (i >= ngroups) return;
    const float4* s4 = (const float4*)src;
    float4 v0 = s4[2 * i], v1 = s4[2 * i + 1];
    u16x8 o;
    o[0] = f2bf(v0.x); o[1] = f2bf(v0.y); o[2] = f2bf(v0.z); o[3] = f2bf(v0.w);
    o[4] = f2bf(v1.x); o[5] = f2bf(v1.y); o[6] = f2bf(v1.z); o[7] = f2bf(v1.w);
    ((u16x8*)dst)[i] = o;
}

// combined = [x, h] as bf16 [BDIM][CDIM]; also pre-fill new_combined's x half
__global__ void pack_combined_kernel(const float* __restrict__ x, const float* __restrict__ h,
                                     u16* __restrict__ comb, u16* __restrict__ newc) {
    int i = blockIdx.x * blockDim.x + threadIdx.x;  // one group of 8 elems
    if (i >= BDIM * (CDIM / 8)) return;
    int b = i >> 9;              // CDIM/8 == 512
    int c = (i & 511) * 8;
    const float* src = (c < IDIM) ? (x + (size_t)b * IDIM + c)
                                  : (h + (size_t)b * HDIM + (c - IDIM));
    float4 v0 = ((const float4*)src)[0], v1 = ((const float4*)src)[1];
    u16x8 o;
    o[0] = f2bf(v0.x); o[1] = f2bf(v0.y); o[2] = f2bf(v0.z); o[3] = f2bf(v0.w);
    o[4] = f2bf(v1.x); o[5] = f2bf(v1.y); o[6] = f2bf(v1.z); o[7] = f2bf(v1.w);
    *(u16x8*)(comb + (size_t)b * CDIM + c) = o;
    if (c < IDIM) *(u16x8*)(newc + (size_t)b * CDIM + c) = o;
}

// ---------------------------------------------------------------------------
// 8-phase (4 phases per K-tile, x2 dbuf) 256-wide GEMM: C = A[M,K]*B[N,K]^T.
// BN=256 fixed, BM in {256,128}. 8 waves as 2(M)x4(N); per-wave out BM/2 x 64.
// K-tile BK=64; quadrants (qm,qn) in phase order (0,0)(0,1)(1,1)(1,0).
// Staging: 64-row chunks, 1 global_load_lds(16B)/thread/chunk, issue order
// A01,B01,B23,A23 (BM=128: A01,B01,B23); counted vmcnt (never 0 in loop).
// LDS k-slot XOR swizzle on BOTH source addr and read addr (round-1: 0 confl).
// EP==1: v=sigmoid(acc+bias); col<HDIM -> newc[r][IDIM+col]=bf16(h*v);
//        col>=HDIM -> Sout[r][col-HDIM]=v
// EP==2: p=tanh(acc+bias0); s=Sout[r][col]; Sout[r][col]=h*(1-s)+p*s
// ---------------------------------------------------------------------------
template <int BM, int EP>
__global__ __launch_bounds__(512, 2) void gemm8p(
        const u16* __restrict__ A, const u16* __restrict__ Bm,
        const float* __restrict__ h,
        const float* __restrict__ bias0, const float* __restrict__ bias1,
        float* __restrict__ Sout, u16* __restrict__ newc) {
    constexpr int MF_H = (BM == 256) ? 4 : 2;    // m-frags per quadrant
    constexpr int QMS  = (BM == 256) ? 128 : 32; // qm row stride
    constexpr int NT   = KDIM / 64;

    const int tid  = threadIdx.x;
    const int lane = tid & 63;
    const int wave = tid >> 6;
    const int wr = wave >> 2, wc = wave & 3;
    const int bm = blockIdx.y * BM;
    const int bn = blockIdx.x * 256;

    __shared__ __align__(16) u16 lA[2][BM * 64];
    __shared__ __align__(16) u16 lB[2][256 * 64];

    f32x4 acc[2 * MF_H][4] = {};
    s16x8 af[MF_H][2];     // current qm's A frags
    s16x8 bq[2][2][2];     // bq[qn][nf][ks] — both qn kept live

    // staged chunk: 64 rows x 64 k. thread t -> row c*64 + t/8, k-slot t%8,
    // source k-slot XOR-swizzled by row&7; LDS dest linear (wave base + lane*16).
    const int srow = tid >> 3;
    const int ssw  = ((tid & 7) ^ ((tid >> 3) & 7)) << 3;

    auto stageA = [&](int nb, int c, int k0) {
        gload_lds16(A + (size_t)(bm + c * 64 + srow) * KDIM + k0 + ssw,
                    &lA[nb][(c * 64 + wave * 8) * 64]);
    };
    auto stageB = [&](int nb, int c, int k0) {
        gload_lds16(Bm + (size_t)(bn + c * 64 + srow) * KDIM + k0 + ssw,
                    &lB[nb][(c * 64 + wave * 8) * 64]);
    };

#define READ_A(QM)                                                              \
    _Pragma("unroll") for (int fm = 0; fm < MF_H; ++fm) {                       \
        const int row_ = wr * 64 + (QM) * QMS + fm * 16 + (lane & 15);          \
        const int bo_ = row_ * 64; const int rx_ = row_ & 7;                    \
        af[fm][0] = *(const s16x8*)&curA[bo_ + ((((lane >> 4)    ) ^ rx_) << 3)]; \
        af[fm][1] = *(const s16x8*)&curA[bo_ + ((((lane >> 4) + 4) ^ rx_) << 3)]; \
    }
#define READ_B(QN)                                                              \
    _Pragma("unroll") for (int nf = 0; nf < 2; ++nf) {                          \
        const int row_ = wc * 32 + (QN) * 128 + nf * 16 + (lane & 15);          \
        const int bo_ = row_ * 64; const int rx_ = row_ & 7;                    \
        bq[QN][nf][0] = *(const s16x8*)&curB[bo_ + ((((lane >> 4)    ) ^ rx_) << 3)]; \
        bq[QN][nf][1] = *(const s16x8*)&curB[bo_ + ((((lane >> 4) + 4) ^ rx_) << 3)]; \
    }
#define MFMA_QUAD(QM, QN)                                                       \
    _Pragma("unroll") for (int ks = 0; ks < 2; ++ks)                            \
    _Pragma("unroll") for (int fm = 0; fm < MF_H; ++fm)                         \
    _Pragma("unroll") for (int nf = 0; nf < 2; ++nf)                            \
        acc[(QM) * MF_H + fm][(QN) * 2 + nf] =                                  \
            __builtin_amdgcn_mfma_f32_16x16x32_bf16(                            \
                af[fm][ks], bq[QN][nf][ks], acc[(QM) * MF_H + fm][(QN) * 2 + nf], 0, 0, 0);
#define PHASE_MID()                                                             \
    __builtin_amdgcn_s_barrier();                                               \
    asm volatile("s_waitcnt lgkmcnt(0)" ::: "memory");                          \
    __builtin_amdgcn_sched_barrier(0);                                          \
    __builtin_amdgcn_s_setprio(1);
#define PHASE_END_NOWAIT()                                                      \
    __builtin_amdgcn_s_setprio(0);                                              \
    __builtin_amdgcn_s_barrier();
#define PHASE_END_WAIT()                                                        \
    __builtin_amdgcn_s_setprio(0);                                              \
    if constexpr (BM == 256) { asm volatile("s_waitcnt vmcnt(4)" ::: "memory"); } \
    else                     { asm volatile("s_waitcnt vmcnt(2)" ::: "memory"); } \
    __builtin_amdgcn_s_barrier();

    // prologue: stage tile 0 in read order, wait for first 4 (A01+B01), barrier
    stageA(0, 0, 0); stageA(0, 1, 0);
    stageB(0, 0, 0); stageB(0, 1, 0); stageB(0, 2, 0); stageB(0, 3, 0);
    if constexpr (BM == 256) { stageA(0, 2, 0); stageA(0, 3, 0); }
    if constexpr (BM == 256) { asm volatile("s_waitcnt vmcnt(4)" ::: "memory"); }
    else                     { asm volatile("s_waitcnt vmcnt(2)" ::: "memory"); }
    __builtin_amdgcn_s_barrier();

    for (int kt = 0; kt < NT; ++kt) {
        const u16* curA = lA[kt & 1];
        const u16* curB = lB[kt & 1];
        const int nb = (kt & 1) ^ 1;
        const int kn = (kt + 1) * 64;
        const bool pf = (kt + 1 < NT);

        // phase 0: reads A(qm0)+B(qn0); stage A01 of next tile; MFMA (0,0)
        READ_A(0)
        READ_B(0)
        if (pf) { stageA(nb, 0, kn); stageA(nb, 1, kn); }
        PHASE_MID();
        MFMA_QUAD(0, 0);
        PHASE_END_WAIT();

        // phase 1: reads B(qn1); stage B01; MFMA (0,1)
        READ_B(1)
        if (pf) { stageB(nb, 0, kn); stageB(nb, 1, kn); }
        PHASE_MID();
        MFMA_QUAD(0, 1);
        if constexpr (BM == 256) { PHASE_END_WAIT(); }
        else                     { PHASE_END_NOWAIT(); }

        // phase 2: reads A(qm1); stage B23; MFMA (1,1)
        READ_A(1)
        if (pf) { stageB(nb, 2, kn); stageB(nb, 3, kn); }
        PHASE_MID();
        MFMA_QUAD(1, 1);
        PHASE_END_NOWAIT();

        // phase 3: no reads; stage A23 (BM=256); MFMA (1,0)
        if constexpr (BM == 256) {
            if (pf) { stageA(nb, 2, kn); stageA(nb, 3, kn); }
        }
        PHASE_MID();
        MFMA_QUAD(1, 0);
        PHASE_END_WAIT();
    }

#undef READ_A
#undef READ_B
#undef MFMA_QUAD
#undef PHASE_MID
#undef PHASE_END_NOWAIT
#undef PHASE_END_WAIT

    // epilogue: D layout col = lane&15, row = (lane>>4)*4 + reg (m89-verified)
    #pragma unroll
    for (int qm = 0; qm < 2; ++qm)
    #pragma unroll
    for (int fm = 0; fm < MF_H; ++fm)
    #pragma unroll
    for (int qn = 0; qn < 2; ++qn)
    #pragma unroll
    for (int nf = 0; nf < 2; ++nf) {
        const int r0  = bm + wr * 64 + qm * QMS + fm * 16 + ((lane >> 4) << 2);
        const int col = bn + wc * 32 + qn * 128 + nf * 16 + (lane & 15);
        const f32x4 a = acc[qm * MF_H + fm][qn * 2 + nf];
        #pragma unroll
        for (int j = 0; j < 4; ++j) {
            const int r = r0 + j;
            const float v = a[j];
            if constexpr (EP == 1) {
                const float bv = (col < HDIM) ? bias0[col] : bias1[col - HDIM];
                const float sgm = 1.0f / (1.0f + __expf(-(v + bv)));
                if (col < HDIM) {
                    const float hv = h[(size_t)r * HDIM + col];
                    newc[(size_t)r * CDIM + IDIM + col] = f2bf(hv * sgm);
                } else {
                    Sout[(size_t)r * HDIM + (col - HDIM)] = sgm;
                }
            } else {
                const float p = tanhf(v + bias0[col]);
                const size_t idx = (size_t)r * HDIM + col;
                const float s = Sout[idx];
                const float hv = h[idx];
                Sout[idx] = hv * (1.0f - s) + p * s;
            }
        }
    }
}

extern "C" void kernel_launch(void* const* d_in, const int* in_sizes, int n_in,
                              void* d_out, int out_size, void* d_ws, size_t ws_size,
                              hipStream_t stream) {
    (void)in_sizes; (void)n_in; (void)out_size; (void)ws_size;
    const float* x  = (const float*)d_in[0];
    const float* h  = (const float*)d_in[1];
    const float* Wu = (const float*)d_in[2];
    const float* bu = (const float*)d_in[3];
    const float* Ws = (const float*)d_in[4];
    const float* bs = (const float*)d_in[5];
    const float* Wp = (const float*)d_in[6];
    const float* bp = (const float*)d_in[7];
    float* out = (float*)d_out;

    // workspace layout (bf16 elements): 112 MB total
    u16* comb  = (u16*)d_ws;                            // [BDIM][CDIM]   32 MB
    u16* newc  = comb  + (size_t)BDIM * CDIM;           // [BDIM][CDIM]   32 MB
    u16* wpack = newc  + (size_t)BDIM * CDIM;           // [2*HDIM][CDIM] 32 MB
    u16* wpred = wpack + (size_t)2 * HDIM * CDIM;       // [HDIM][CDIM]   16 MB

    const int WG = 256;
    const int wgrp = (HDIM * CDIM) / 8;                 // 1M groups per weight
    cvt_bf16_kernel<<<wgrp / WG, WG, 0, stream>>>(Wu, wpack, wgrp);
    cvt_bf16_kernel<<<wgrp / WG, WG, 0, stream>>>(Ws, wpack + (size_t)HDIM * CDIM, wgrp);
    cvt_bf16_kernel<<<wgrp / WG, WG, 0, stream>>>(Wp, wpred, wgrp);
    const int cgrp = (BDIM * CDIM) / 8;                 // 2M groups
    pack_combined_kernel<<<cgrp / WG, WG, 0, stream>>>(x, h, comb, newc);

    // GEMM1: [x,h] @ [Wu;Ws]^T -> sigmoid -> updated (bf16 into newc) + S (f32 into out)
    gemm8p<256, 1><<<dim3(CDIM / 256, BDIM / 256), 512, 0, stream>>>(
        comb, wpack, h, bu, bs, out, newc);
    // GEMM2: [x,updated] @ Wp^T -> tanh -> h_new (f32 into out, reading S in place)
    gemm8p<128, 2><<<dim3(HDIM / 256, BDIM / 128), 512, 0, stream>>>(
        newc, wpred, h, bp, nullptr, out, nullptr);
}

// Round 3
// 286.774 us; speedup vs baseline: 1.1577x; 1.1577x over previous
//
#include <hip/hip_runtime.h>
#include <stdint.h>

#define IDIM 2048
#define HDIM 2048
#define CDIM 4096
#define BDIM 4096
#define KDIM 4096

typedef float f32x4 __attribute__((ext_vector_type(4)));
typedef short s16x8 __attribute__((ext_vector_type(8)));
typedef unsigned short u16;
typedef u16 u16x8 __attribute__((ext_vector_type(8)));

__device__ __forceinline__ u16 f2bf(float f) {
    union { float f; uint32_t u; } v; v.f = f;
    uint32_t r = v.u + 0x7fffu + ((v.u >> 16) & 1u);  // round-to-nearest-even
    return (u16)(r >> 16);
}

__device__ __forceinline__ void gload_lds16(const void* g, void* l) {
    __builtin_amdgcn_global_load_lds(
        (__attribute__((address_space(1))) void*)g,
        (__attribute__((address_space(3))) void*)l,
        16, 0, 0);
}

// flat f32 -> bf16 convert, 8 elements per thread
__global__ void cvt_bf16_kernel(const float* __restrict__ src, u16* __restrict__ dst,
                                int ngroups) {
    int i = blockIdx.x * blockDim.x + threadIdx.x;
    if (i >= ngroups) return;
    const float4* s4 = (const float4*)src;
    float4 v0 = s4[2 * i], v1 = s4[2 * i + 1];
    u16x8 o;
    o[0] = f2bf(v0.x); o[1] = f2bf(v0.y); o[2] = f2bf(v0.z); o[3] = f2bf(v0.w);
    o[4] = f2bf(v1.x); o[5] = f2bf(v1.y); o[6] = f2bf(v1.z); o[7] = f2bf(v1.w);
    ((u16x8*)dst)[i] = o;
}

// combined = [x, h] as bf16 [BDIM][CDIM]; also pre-fill new_combined's x half
__global__ void pack_combined_kernel(const float* __restrict__ x, const float* __restrict__ h,
                                     u16* __restrict__ comb, u16* __restrict__ newc) {
    int i = blockIdx.x * blockDim.x + threadIdx.x;  // one group of 8 elems
    if (i >= BDIM * (CDIM / 8)) return;
    int b = i >> 9;              // CDIM/8 == 512
    int c = (i & 511) * 8;
    const float* src = (c < IDIM) ? (x + (size_t)b * IDIM + c)
                                  : (h + (size_t)b * HDIM + (c - IDIM));
    float4 v0 = ((const float4*)src)[0], v1 = ((const float4*)src)[1];
    u16x8 o;
    o[0] = f2bf(v0.x); o[1] = f2bf(v0.y); o[2] = f2bf(v0.z); o[3] = f2bf(v0.w);
    o[4] = f2bf(v1.x); o[5] = f2bf(v1.y); o[6] = f2bf(v1.z); o[7] = f2bf(v1.w);
    *(u16x8*)(comb + (size_t)b * CDIM + c) = o;
    if (c < IDIM) *(u16x8*)(newc + (size_t)b * CDIM + c) = o;
}

// ---------------------------------------------------------------------------
// GEMM1 (proven round-1, 905 TF): C = A[M,K]*B[N,K]^T, 128x128 tile, BK=64,
// 4 waves (2x2), wave out 64x64 (4x4 frags of 16x16x32). global_load_lds w=16
// with XOR k-slot swizzle on source + read (0 bank conflicts measured).
// Epilogue: v=sigmoid(acc+bias); col<HDIM -> newc[r][IDIM+col]=bf16(h*v);
//           col>=HDIM -> Sout[r][col-HDIM]=v
// ---------------------------------------------------------------------------
__global__ void gemm_bt1(const u16* __restrict__ A, const u16* __restrict__ Bm,
                         const float* __restrict__ h,
                         const float* __restrict__ bias0, const float* __restrict__ bias1,
                         float* __restrict__ Sout, u16* __restrict__ newc) {
    constexpr int BM = 128, BK = 64;
    const int tid  = threadIdx.x;
    const int lane = tid & 63;
    const int wave = tid >> 6;
    const int wr = wave >> 1, wc = wave & 1;
    const int bm = blockIdx.y * BM;
    const int bn = blockIdx.x * BM;

    __shared__ __align__(16) u16 lA[BM * BK];
    __shared__ __align__(16) u16 lB[BM * BK];

    f32x4 acc[4][4] = {};

    const int srow = wave * 32 + (lane >> 3);       // staged row (per i: +8*i)
    const int sg   = (lane & 7) ^ (lane >> 3);      // swizzled source k-slot

    auto stage = [&](int k0) {
        #pragma unroll
        for (int i = 0; i < 4; ++i) {
            const int r = srow + i * 8;
            gload_lds16(A  + (size_t)(bm + r) * KDIM + k0 + sg * 8,
                        &lA[(wave * 32 + i * 8) * 64]);
            gload_lds16(Bm + (size_t)(bn + r) * KDIM + k0 + sg * 8,
                        &lB[(wave * 32 + i * 8) * 64]);
        }
    };

    stage(0);
    constexpr int NT = KDIM / BK;
    for (int kt = 0; kt < NT; ++kt) {
        __syncthreads();   // drains global_load_lds (vmcnt) + all waves ready
        #pragma unroll
        for (int ks = 0; ks < 2; ++ks) {
            s16x8 af[4], bfr[4];
            #pragma unroll
            for (int m = 0; m < 4; ++m) {
                const int row = wr * 64 + m * 16 + (lane & 15);
                const int j   = ks * 4 + (lane >> 4);
                af[m] = *(const s16x8*)&lA[row * 64 + ((j ^ (row & 7)) << 3)];
            }
            #pragma unroll
            for (int n = 0; n < 4; ++n) {
                const int row = wc * 64 + n * 16 + (lane & 15);
                const int j   = ks * 4 + (lane >> 4);
                bfr[n] = *(const s16x8*)&lB[row * 64 + ((j ^ (row & 7)) << 3)];
            }
            #pragma unroll
            for (int m = 0; m < 4; ++m)
                #pragma unroll
                for (int n = 0; n < 4; ++n)
                    acc[m][n] = __builtin_amdgcn_mfma_f32_16x16x32_bf16(
                        af[m], bfr[n], acc[m][n], 0, 0, 0);
        }
        __syncthreads();   // all reads done before restage
        if (kt + 1 < NT) stage((kt + 1) * BK);
    }

    // epilogue: D layout col = lane&15, row = (lane>>4)*4 + reg (m89-verified)
    #pragma unroll
    for (int m = 0; m < 4; ++m) {
        const int r0 = bm + wr * 64 + m * 16 + ((lane >> 4) << 2);
        #pragma unroll
        for (int n = 0; n < 4; ++n) {
            const int col = bn + wc * 64 + n * 16 + (lane & 15);
            #pragma unroll
            for (int j = 0; j < 4; ++j) {
                const int r = r0 + j;
                const float v = acc[m][n][j];
                const float bv = (col < HDIM) ? bias0[col] : bias1[col - HDIM];
                const float sgm = 1.0f / (1.0f + __expf(-(v + bv)));
                if (col < HDIM) {
                    const float hv = h[(size_t)r * HDIM + col];
                    newc[(size_t)r * CDIM + IDIM + col] = f2bf(hv * sgm);
                } else {
                    Sout[(size_t)r * HDIM + (col - HDIM)] = sgm;
                }
            }
        }
    }
}

// ---------------------------------------------------------------------------
// GEMM2: same m97 per-wave structure but BM=128, BN=64 so grid = 32x32 = 1024
// blocks (4/CU — round-1's GEMM2 at BN=128 had only 512 blocks = 2/CU and
// ran at 464 TF vs GEMM1's 905; blocks/CU is the overlap lever here).
// 4 waves (2x2), wave out 64x32 (4x2 frags). LDS 24 KiB.
// Epilogue: p=tanh(acc+bias); s=Sout[r][col]; Sout[r][col]=h*(1-s)+p*s
// ---------------------------------------------------------------------------
__global__ void gemm_bt2(const u16* __restrict__ A, const u16* __restrict__ Bm,
                         const float* __restrict__ h,
                         const float* __restrict__ bias0,
                         float* __restrict__ Sout) {
    constexpr int BM = 128, BN = 64, BK = 64;
    const int tid  = threadIdx.x;
    const int lane = tid & 63;
    const int wave = tid >> 6;
    const int wr = wave >> 1, wc = wave & 1;
    const int bm = blockIdx.y * BM;
    const int bn = blockIdx.x * BN;

    __shared__ __align__(16) u16 lA[BM * BK];
    __shared__ __align__(16) u16 lB[BN * BK];

    f32x4 acc[4][2] = {};

    const int sg = (lane & 7) ^ (lane >> 3);        // swizzled source k-slot

    auto stage = [&](int k0) {
        #pragma unroll
        for (int i = 0; i < 4; ++i) {               // A: 32 rows per wave
            const int r = wave * 32 + i * 8 + (lane >> 3);
            gload_lds16(A + (size_t)(bm + r) * KDIM + k0 + sg * 8,
                        &lA[(wave * 32 + i * 8) * 64]);
        }
        #pragma unroll
        for (int i = 0; i < 2; ++i) {               // B: 16 rows per wave
            const int r = wave * 16 + i * 8 + (lane >> 3);
            gload_lds16(Bm + (size_t)(bn + r) * KDIM + k0 + sg * 8,
                        &lB[(wave * 16 + i * 8) * 64]);
        }
    };

    stage(0);
    constexpr int NT = KDIM / BK;
    for (int kt = 0; kt < NT; ++kt) {
        __syncthreads();
        #pragma unroll
        for (int ks = 0; ks < 2; ++ks) {
            s16x8 af[4], bfr[2];
            #pragma unroll
            for (int m = 0; m < 4; ++m) {
                const int row = wr * 64 + m * 16 + (lane & 15);
                const int j   = ks * 4 + (lane >> 4);
                af[m] = *(const s16x8*)&lA[row * 64 + ((j ^ (row & 7)) << 3)];
            }
            #pragma unroll
            for (int n = 0; n < 2; ++n) {
                const int row = wc * 32 + n * 16 + (lane & 15);
                const int j   = ks * 4 + (lane >> 4);
                bfr[n] = *(const s16x8*)&lB[row * 64 + ((j ^ (row & 7)) << 3)];
            }
            #pragma unroll
            for (int m = 0; m < 4; ++m)
                #pragma unroll
                for (int n = 0; n < 2; ++n)
                    acc[m][n] = __builtin_amdgcn_mfma_f32_16x16x32_bf16(
                        af[m], bfr[n], acc[m][n], 0, 0, 0);
        }
        __syncthreads();
        if (kt + 1 < NT) stage((kt + 1) * BK);
    }

    #pragma unroll
    for (int m = 0; m < 4; ++m) {
        const int r0 = bm + wr * 64 + m * 16 + ((lane >> 4) << 2);
        #pragma unroll
        for (int n = 0; n < 2; ++n) {
            const int col = bn + wc * 32 + n * 16 + (lane & 15);
            #pragma unroll
            for (int j = 0; j < 4; ++j) {
                const int r = r0 + j;
                const float p = tanhf(acc[m][n][j] + bias0[col]);
                const size_t idx = (size_t)r * HDIM + col;
                const float s  = Sout[idx];
                const float hv = h[idx];
                Sout[idx] = hv * (1.0f - s) + p * s;
            }
        }
    }
}

extern "C" void kernel_launch(void* const* d_in, const int* in_sizes, int n_in,
                              void* d_out, int out_size, void* d_ws, size_t ws_size,
                              hipStream_t stream) {
    (void)in_sizes; (void)n_in; (void)out_size; (void)ws_size;
    const float* x  = (const float*)d_in[0];
    const float* h  = (const float*)d_in[1];
    const float* Wu = (const float*)d_in[2];
    const float* bu = (const float*)d_in[3];
    const float* Ws = (const float*)d_in[4];
    const float* bs = (const float*)d_in[5];
    const float* Wp = (const float*)d_in[6];
    const float* bp = (const float*)d_in[7];
    float* out = (float*)d_out;

    // workspace layout (bf16 elements): 112 MB total
    u16* comb  = (u16*)d_ws;                            // [BDIM][CDIM]   32 MB
    u16* newc  = comb  + (size_t)BDIM * CDIM;           // [BDIM][CDIM]   32 MB
    u16* wpack = newc  + (size_t)BDIM * CDIM;           // [2*HDIM][CDIM] 32 MB
    u16* wpred = wpack + (size_t)2 * HDIM * CDIM;       // [HDIM][CDIM]   16 MB

    const int WG = 256;
    const int wgrp = (HDIM * CDIM) / 8;                 // 1M groups per weight
    cvt_bf16_kernel<<<wgrp / WG, WG, 0, stream>>>(Wu, wpack, wgrp);
    cvt_bf16_kernel<<<wgrp / WG, WG, 0, stream>>>(Ws, wpack + (size_t)HDIM * CDIM, wgrp);
    cvt_bf16_kernel<<<wgrp / WG, WG, 0, stream>>>(Wp, wpred, wgrp);
    const int cgrp = (BDIM * CDIM) / 8;                 // 2M groups
    pack_combined_kernel<<<cgrp / WG, WG, 0, stream>>>(x, h, comb, newc);

    // GEMM1: [x,h] @ [Wu;Ws]^T -> sigmoid -> updated (bf16 into newc) + S (f32 into out)
    gemm_bt1<<<dim3(CDIM / 128, BDIM / 128), 256, 0, stream>>>(
        comb, wpack, h, bu, bs, out, newc);
    // GEMM2: [x,updated] @ Wp^T -> tanh -> h_new (f32 into out, reading S in place)
    gemm_bt2<<<dim3(HDIM / 64, BDIM / 128), 256, 0, stream>>>(
        newc, wpred, h, bp, out);
}